// Round 17
// baseline (114.106 us; speedup 1.0000x reference)
//
#include <hip/hip_runtime.h>
#include <hip/hip_bf16.h>
#include <stdint.h>

#define NB 2
#define NS 2048
#define NDM 1024
#define NH 16
#define NHD 64
#define NTOK (NB * NS)  // 4096

typedef __bf16 bf16x8 __attribute__((ext_vector_type(8)));
typedef float f32x4 __attribute__((ext_vector_type(4)));
typedef uint16_t u16x8 __attribute__((ext_vector_type(8)));

static __device__ __forceinline__ uint16_t f2bf(float f) {
  __bf16 b = (__bf16)f;
  union { __bf16 b; uint16_t u; } x; x.b = b;
  return x.u;
}

static __device__ __forceinline__ u16x8 cvt8(float4 a, float4 b) {
  u16x8 v;
  v[0] = f2bf(a.x); v[1] = f2bf(a.y); v[2] = f2bf(a.z); v[3] = f2bf(a.w);
  v[4] = f2bf(b.x); v[5] = f2bf(b.y); v[6] = f2bf(b.z); v[7] = f2bf(b.w);
  return v;
}

static __device__ __forceinline__ void gload_lds16(const void* g, void* l) {
  __builtin_amdgcn_global_load_lds(
      (const __attribute__((address_space(1))) void*)g,
      (__attribute__((address_space(3))) void*)l, 16, 0, 0);
}

// ---------------------------------------------------------------------------
// Single fp32->bf16 convert pass over the 16M-element concat.
// ---------------------------------------------------------------------------
__global__ __launch_bounds__(256) void cvt_all(
    const float* __restrict__ wq, const float* __restrict__ wk,
    const float* __restrict__ wv, const float* __restrict__ wo,
    const float* __restrict__ q, const float* __restrict__ k,
    const float* __restrict__ v, uint16_t* __restrict__ WQB,
    uint16_t* __restrict__ WKB, uint16_t* __restrict__ WVB,
    uint16_t* __restrict__ WOB, uint16_t* __restrict__ XBQ,
    uint16_t* __restrict__ XBK, uint16_t* __restrict__ XBV) {
  size_t E = ((size_t)blockIdx.x * 256 + threadIdx.x) * 8;
  const float* src;
  uint16_t* dst;
  size_t off;
  if (E < (size_t)(4u << 20)) {
    int s = (int)(E >> 20);
    off = E & ((1u << 20) - 1);
    src = (s == 0) ? wq : (s == 1) ? wk : (s == 2) ? wv : wo;
    dst = (s == 0) ? WQB : (s == 1) ? WKB : (s == 2) ? WVB : WOB;
  } else {
    size_t E2 = E - ((size_t)4u << 20);
    int s = (int)(E2 >> 22);
    off = E2 & ((1u << 22) - 1);
    src = (s == 0) ? q : (s == 1) ? k : v;
    dst = (s == 0) ? XBQ : (s == 1) ? XBK : XBV;
  }
  float4 a = *(const float4*)(src + off);
  float4 b = *(const float4*)(src + off + 4);
  *(u16x8*)&dst[off] = cvt8(a, b);
}

// ---------------------------------------------------------------------------
// Projections: R13 structure + XCD-grouped 1D block mapping (T1).
// 768 blocks = 8 XCD groups x 96; XCD c handles (z,y) combos c*3..c*3+2 with
// all 32 m-blocks -> each W panel (256KB) stays in ONE XCD's L2.
// ---------------------------------------------------------------------------
__global__ __launch_bounds__(256) void proj_gemm(
    const uint16_t* __restrict__ xbq, const uint16_t* __restrict__ xbk,
    const uint16_t* __restrict__ xbv, const uint16_t* __restrict__ wqb,
    const uint16_t* __restrict__ wkb, const uint16_t* __restrict__ wvb,
    uint16_t* __restrict__ XQ, uint16_t* __restrict__ XK,
    uint16_t* __restrict__ XVT) {
  __shared__ uint16_t SM[2][2][128][64];
  // XCD-grouped decode: c = XCD slot (dispatch round-robin), r = seq in slot
  int bid = (int)blockIdx.x;
  int c = bid & 7, r = bid >> 3;        // r: 0..95
  int combo = c * 3 + (r >> 5);         // 0..23 = (z,y)
  int z = combo >> 3, yy = combo & 7;
  int m0 = (r & 31) * 128, n0 = yy * 128;

  const uint16_t* A = (z == 0) ? xbq : (z == 1) ? xbk : xbv;
  const uint16_t* W = (z == 0) ? wqb : (z == 1) ? wkb : wvb;
  int tid = threadIdx.x;
  int lane = tid & 63, w = tid >> 6;
  int g = lane >> 4, r16 = lane & 15;
  int wm = w >> 1, wn = w & 1;
  int bce = ((lane & 7) ^ ((lane >> 3) & 7)) * 8;
  int brlane = lane >> 3;

  f32x4 acc[4][4] = {};

  #pragma unroll
  for (int i = 0; i < 4; ++i) {
    int row = w * 32 + i * 8;
    gload_lds16(A + (size_t)(m0 + row + brlane) * NDM + bce, &SM[0][0][row][0]);
    gload_lds16(W + (size_t)(n0 + row + brlane) * NDM + bce, &SM[0][1][row][0]);
  }
  __syncthreads();

  for (int t = 0; t < 16; ++t) {
    int cur = t & 1, nxt = cur ^ 1;
    if (t < 15) {
      int k1 = (t + 1) * 64;
      #pragma unroll
      for (int i = 0; i < 4; ++i) {
        int row = w * 32 + i * 8;
        gload_lds16(A + (size_t)(m0 + row + brlane) * NDM + k1 + bce,
                    &SM[nxt][0][row][0]);
        gload_lds16(W + (size_t)(n0 + row + brlane) * NDM + k1 + bce,
                    &SM[nxt][1][row][0]);
      }
    }

    #pragma unroll
    for (int kc = 0; kc < 2; ++kc) {
      bf16x8 af[4], bf[4];
      #pragma unroll
      for (int i = 0; i < 4; ++i) {
        int gran = (kc * 4 + g) ^ (r16 & 7);
        af[i] = *(const bf16x8*)&SM[cur][0][wm * 64 + i * 16 + r16][gran * 8];
        bf[i] = *(const bf16x8*)&SM[cur][1][wn * 64 + i * 16 + r16][gran * 8];
      }
      #pragma unroll
      for (int mi = 0; mi < 4; ++mi)
        #pragma unroll
        for (int ni = 0; ni < 4; ++ni)
          acc[mi][ni] = __builtin_amdgcn_mfma_f32_16x16x32_bf16(
              af[mi], bf[ni], acc[mi][ni], 0, 0, 0);
    }
    __syncthreads();
  }

  if (z == 2) {
    uint16_t* T = &SM[0][0][0][0];
    #pragma unroll
    for (int mi = 0; mi < 4; ++mi) {
      #pragma unroll
      for (int ni = 0; ni < 4; ++ni) {
        int tr = wn * 64 + ni * 16 + r16;
        int tc = wm * 64 + mi * 16 + g * 4;
        int gran = tc >> 3, sub = g & 1;
        f32x4 a = acc[mi][ni];
        ushort4 pk;
        pk.x = f2bf(a[0]); pk.y = f2bf(a[1]);
        pk.z = f2bf(a[2]); pk.w = f2bf(a[3]);
        *(ushort4*)(T + tr * 128 + ((gran ^ (tr & 7)) << 3) + (sub << 2)) = pk;
      }
    }
    __syncthreads();
    #pragma unroll
    for (int it = 0; it < 8; ++it) {
      int row = it * 16 + (tid >> 4);
      int grn = tid & 15;
      u16x8 vv = *(const u16x8*)(T + row * 128 + ((grn ^ (row & 7)) << 3));
      *(u16x8*)&XVT[(size_t)(n0 + row) * NTOK + m0 + grn * 8] = vv;
    }
  } else {
    float scale = (z == 0) ? 0.125f * 1.44269504088896340736f : 1.0f;
    uint16_t* Y = (z == 0) ? XQ : XK;
    #pragma unroll
    for (int mi = 0; mi < 4; ++mi) {
      #pragma unroll
      for (int ni = 0; ni < 4; ++ni) {
        int m = m0 + wm * 64 + mi * 16 + g * 4;
        int n = n0 + wn * 64 + ni * 16 + r16;
        f32x4 a = acc[mi][ni];
        #pragma unroll
        for (int j = 0; j < 4; ++j)
          Y[(size_t)(m + j) * NDM + n] = f2bf(a[j] * scale);
      }
    }
  }
}

// ---------------------------------------------------------------------------
// Causal flash attention v12 — R16 + diagonal-subtile skip.
// On the diagonal tile (t == T-1), wave w's active kv-subtiles are t4 <= w;
// the rest are fully masked -> skip their K ds_reads + QK MFMAs (sc preset
// to -1e30, p underflows to 0 exactly as before).  Wave-uniform branch.
// ---------------------------------------------------------------------------
__global__ __launch_bounds__(256) void attn_kernel(
    const uint16_t* __restrict__ XQ, const uint16_t* __restrict__ XK,
    const uint16_t* __restrict__ XVT, uint16_t* __restrict__ AO) {
  __shared__ uint16_t Klds[2][64][64];   // [buf][kv][d] linear (gload dest)
  __shared__ uint16_t Vlds[2][64][64];   // [buf][d][kv]
  __shared__ uint16_t Plds[4][16][72];

  int tid = threadIdx.x;
  int lane = tid & 63;
  int w = tid >> 6;
  int g = lane >> 4, r16 = lane & 15;
  int swz = r16 & 7;

  int item = (int)blockIdx.x;
  int qc = 31 - (item >> 5);    // heavy chunks dispatch first
  int bh = item & 31;
  int b = bh >> 4, h = bh & 15;
  int q0 = qc * 64;
  int q0w = q0 + w * 16;
  int T = qc + 1;               // kv tiles of 64

  const uint16_t* qb =
      XQ + (size_t)(b * NS + q0w + r16) * NDM + h * NHD + g * 8;
  bf16x8 qf0 = *(const bf16x8*)qb;
  bf16x8 qf1 = *(const bf16x8*)(qb + 32);

  f32x4 oacc[4] = {};               // O[q=g*4+j][d=dt*16+r16]
  float mrow = -1e30f, lsum = 0.f;  // per-lane: q = r16

  int srl = lane >> 3;
  int bce = ((lane & 7) ^ srl) * 8;
  const uint16_t* kstg = XK + (size_t)(b * NS + srl) * NDM + h * NHD + bce;
  const uint16_t* vstg = XVT + (size_t)(h * NHD + srl) * NTOK + b * NS + bce;
  int stgrow = (w & 1) * 32;

  // prologue: stage tile 0 into buf 0 (waves 0-1: K, waves 2-3: V)
  if (w < 2) {
    #pragma unroll
    for (int i = 0; i < 4; ++i)
      gload_lds16(kstg + (size_t)(stgrow + i * 8) * NDM,
                  &Klds[0][stgrow + i * 8][0]);
  } else {
    #pragma unroll
    for (int i = 0; i < 4; ++i)
      gload_lds16(vstg + (size_t)(stgrow + i * 8) * NTOK,
                  &Vlds[0][stgrow + i * 8][0]);
  }

  for (int t = 0; t < T; ++t) {
    int kv0 = t * 64;
    int cur = t & 1;
    __syncthreads();  // drains stage gloads for tile t; prev-buf reads done
    if (t + 1 < T) {
      int kv1 = kv0 + 64;
      if (w < 2) {
        #pragma unroll
        for (int i = 0; i < 4; ++i)
          gload_lds16(kstg + (size_t)(kv1 + stgrow + i * 8) * NDM,
                      &Klds[cur ^ 1][stgrow + i * 8][0]);
      } else {
        #pragma unroll
        for (int i = 0; i < 4; ++i)
          gload_lds16(vstg + kv1 + (size_t)(stgrow + i * 8) * NTOK,
                      &Vlds[cur ^ 1][stgrow + i * 8][0]);
      }
    }

    // diagonal-tile subtile count: wave-uniform, t4 <= w active on diag
    int nt4 = (t == T - 1) ? (w + 1) : 4;

    // ---- QK^T swapped: col=r16=q, row=g*4+j=kv_local ----
    f32x4 sc[4];
    __builtin_amdgcn_s_setprio(1);
    #pragma unroll
    for (int t4 = 0; t4 < 4; ++t4) {
      if (t4 < nt4) {  // wave-uniform
        bf16x8 kf0 = *(const bf16x8*)&Klds[cur][t4 * 16 + r16][(g ^ swz) * 8];
        bf16x8 kf1 = *(const bf16x8*)&Klds[cur][t4 * 16 + r16][((4 + g) ^ swz) * 8];
        f32x4 x = __builtin_amdgcn_mfma_f32_16x16x32_bf16(
            kf0, qf0, (f32x4){0.f, 0.f, 0.f, 0.f}, 0, 0, 0);
        x = __builtin_amdgcn_mfma_f32_16x16x32_bf16(kf1, qf1, x, 0, 0, 0);
        sc[t4] = x;
      } else {
        sc[t4] = (f32x4){-1e30f, -1e30f, -1e30f, -1e30f};
      }
    }
    __builtin_amdgcn_s_setprio(0);

    // ---- causal mask (diag subtiles only; kv = kv0+t4*16+g*4+j, q = r16) ----
    #pragma unroll
    for (int t4 = 0; t4 < 4; ++t4) {
      if (t4 < nt4 && kv0 + t4 * 16 + 15 > q0w) {  // wave-uniform guard
        #pragma unroll
        for (int j = 0; j < 4; ++j)
          if (kv0 + t4 * 16 + g * 4 + j > q0w + r16) sc[t4][j] = -1e30f;
      }
    }

    // ---- lane-local row max + cross-group combine ----
    float m16 = fmaxf(
        fmaxf(fmaxf(fmaxf(sc[0][0], sc[0][1]), fmaxf(sc[0][2], sc[0][3])),
              fmaxf(fmaxf(sc[1][0], sc[1][1]), fmaxf(sc[1][2], sc[1][3]))),
        fmaxf(fmaxf(fmaxf(sc[2][0], sc[2][1]), fmaxf(sc[2][2], sc[2][3])),
              fmaxf(fmaxf(sc[3][0], sc[3][1]), fmaxf(sc[3][2], sc[3][3]))));
    m16 = fmaxf(m16, __shfl_xor(m16, 16));
    m16 = fmaxf(m16, __shfl_xor(m16, 32));

    // ---- T13 defer-rescale (THR=8 in exp2 domain) ----
    if (!__all(m16 <= mrow + 8.0f)) {
      float mnew = fmaxf(mrow, m16);
      float sf = __builtin_amdgcn_exp2f(mrow - mnew);
      mrow = mnew;
      lsum *= sf;
      #pragma unroll
      for (int j = 0; j < 4; ++j) {
        float sfj = __shfl(sf, g * 4 + j);
        #pragma unroll
        for (int dt = 0; dt < 4; ++dt) oacc[dt][j] *= sfj;
      }
    }

    // ---- P = exp2(S - m), per-lane partial sum, pack to LDS ----
    #pragma unroll
    for (int t4 = 0; t4 < 4; ++t4) {
      float p0 = __builtin_amdgcn_exp2f(sc[t4][0] - mrow);
      float p1 = __builtin_amdgcn_exp2f(sc[t4][1] - mrow);
      float p2 = __builtin_amdgcn_exp2f(sc[t4][2] - mrow);
      float p3 = __builtin_amdgcn_exp2f(sc[t4][3] - mrow);
      lsum += (p0 + p1) + (p2 + p3);
      ushort4 pk;
      pk.x = f2bf(p0); pk.y = f2bf(p1); pk.z = f2bf(p2); pk.w = f2bf(p3);
      *(ushort4*)&Plds[w][r16][t4 * 16 + g * 4] = pk;
    }

    // ---- PV ----
    bf16x8 pa0 = *(const bf16x8*)&Plds[w][r16][g * 8];
    bf16x8 pa1 = *(const bf16x8*)&Plds[w][r16][32 + g * 8];
    __builtin_amdgcn_s_setprio(1);
    #pragma unroll
    for (int dt = 0; dt < 4; ++dt) {
      bf16x8 vf0 = *(const bf16x8*)&Vlds[cur][dt * 16 + r16][(g ^ swz) * 8];
      bf16x8 vf1 = *(const bf16x8*)&Vlds[cur][dt * 16 + r16][((4 + g) ^ swz) * 8];
      oacc[dt] = __builtin_amdgcn_mfma_f32_16x16x32_bf16(pa0, vf0, oacc[dt], 0, 0, 0);
      oacc[dt] = __builtin_amdgcn_mfma_f32_16x16x32_bf16(pa1, vf1, oacc[dt], 0, 0, 0);
    }
    __builtin_amdgcn_s_setprio(0);
  }

  // ---- epilogue: cross-group l reduce, redistribute, normalize, store ----
  float l2 = lsum + __shfl_xor(lsum, 16);
  float ltot = l2 + __shfl_xor(l2, 32);
  #pragma unroll
  for (int j = 0; j < 4; ++j) {
    float lt = __shfl(ltot, g * 4 + j);
    float inv = 1.0f / lt;
    size_t ro = (size_t)(b * NS + q0 + w * 16 + g * 4 + j) * NDM + h * NHD;
    #pragma unroll
    for (int dt = 0; dt < 4; ++dt)
      AO[ro + dt * 16 + r16] = f2bf(oacc[dt][j] * inv);
  }
}

// ---------------------------------------------------------------------------
// Output projection: R13 structure + XCD-grouped mapping (256 = 8 x 32:
// XCD c owns n-panel c with all 32 m-blocks).
// ---------------------------------------------------------------------------
__global__ __launch_bounds__(256) void out_gemm(
    const uint16_t* __restrict__ AO, const uint16_t* __restrict__ wob,
    float* __restrict__ out) {
  __shared__ uint16_t As[2][128][64];
  __shared__ uint16_t Bs[2][128][64];
  int bid = (int)blockIdx.x;
  int m0 = (bid >> 3) * 128, n0 = (bid & 7) * 128;
  int tid = threadIdx.x;
  int lane = tid & 63, w = tid >> 6;
  int g = lane >> 4, r16 = lane & 15;
  int wm = w >> 1, wn = w & 1;
  int bce = ((lane & 7) ^ ((lane >> 3) & 7)) * 8;
  int brlane = lane >> 3;

  f32x4 acc[4][4] = {};

  #pragma unroll
  for (int i = 0; i < 4; ++i) {
    int row = w * 32 + i * 8;
    gload_lds16(AO + (size_t)(m0 + row + brlane) * NDM + bce, &As[0][row][0]);
    gload_lds16(wob + (size_t)(n0 + row + brlane) * NDM + bce, &Bs[0][row][0]);
  }
  __syncthreads();

  for (int t = 0; t < 16; ++t) {
    int cur = t & 1, nxt = cur ^ 1;
    if (t < 15) {
      int k1 = (t + 1) * 64;
      #pragma unroll
      for (int i = 0; i < 4; ++i) {
        int row = w * 32 + i * 8;
        gload_lds16(AO + (size_t)(m0 + row + brlane) * NDM + k1 + bce,
                    &As[nxt][row][0]);
        gload_lds16(wob + (size_t)(n0 + row + brlane) * NDM + k1 + bce,
                    &Bs[nxt][row][0]);
      }
    }

    #pragma unroll
    for (int kc = 0; kc < 2; ++kc) {
      bf16x8 af[4], bf[4];
      #pragma unroll
      for (int i = 0; i < 4; ++i) {
        int gran = (kc * 4 + g) ^ (r16 & 7);
        af[i] = *(const bf16x8*)&As[cur][wm * 64 + i * 16 + r16][gran * 8];
        bf[i] = *(const bf16x8*)&Bs[cur][wn * 64 + i * 16 + r16][gran * 8];
      }
      #pragma unroll
      for (int mi = 0; mi < 4; ++mi)
        #pragma unroll
        for (int ni = 0; ni < 4; ++ni)
          acc[mi][ni] = __builtin_amdgcn_mfma_f32_16x16x32_bf16(
              af[mi], bf[ni], acc[mi][ni], 0, 0, 0);
    }
    __syncthreads();
  }

  #pragma unroll
  for (int mi = 0; mi < 4; ++mi) {
    #pragma unroll
    for (int ni = 0; ni < 4; ++ni) {
      int m = m0 + wm * 64 + mi * 16 + g * 4;
      int n = n0 + wn * 64 + ni * 16 + r16;
      #pragma unroll
      for (int j = 0; j < 4; ++j)
        out[(size_t)(m + j) * NDM + n] = acc[mi][ni][j];
    }
  }
}

extern "C" void kernel_launch(void* const* d_in, const int* in_sizes, int n_in,
                              void* d_out, int out_size, void* d_ws,
                              size_t ws_size, hipStream_t stream) {
  const float* q  = (const float*)d_in[0];
  const float* k  = (const float*)d_in[1];
  const float* v  = (const float*)d_in[2];
  const float* wq = (const float*)d_in[3];
  const float* wk = (const float*)d_in[4];
  const float* wv = (const float*)d_in[5];
  const float* wo = (const float*)d_in[6];

  const size_t XN = (size_t)NTOK * NDM;  // 4M elems
  const size_t WN = (size_t)NDM * NDM;   // 1M elems
  uint16_t* XQ  = (uint16_t*)d_ws;       // [NTOK][NDM] bf16 (pre-scaled)
  uint16_t* XK  = XQ + XN;               // [NTOK][NDM]
  uint16_t* XVT = XK + XN;               // [NDM][NTOK]
  uint16_t* WQB = XVT + XN;              // bf16 weights, 4 x [NDM][NDM]
  uint16_t* WKB = WQB + WN;
  uint16_t* WVB = WKB + WN;
  uint16_t* WOB = WVB + WN;
  uint16_t* XBQ = WOB + WN;              // bf16 activations, 3 x [NTOK][NDM]
  uint16_t* XBK = XBQ + XN;
  uint16_t* XBV = XBK + XN;
  uint16_t* AO  = XBQ;  // alias: XBQ dead after proj_gemm

  cvt_all<<<dim3(8192), 256, 0, stream>>>(
      wq, wk, wv, wo, q, k, v, WQB, WKB, WVB, WOB, XBQ, XBK, XBV);
  proj_gemm<<<dim3(768), 256, 0, stream>>>(
      XBQ, XBK, XBV, WQB, WKB, WVB, XQ, XK, XVT);
  attn_kernel<<<dim3(1024), 256, 0, stream>>>(XQ, XK, XVT, AO);
  out_gemm<<<dim3(256), 256, 0, stream>>>(
      AO, WOB, (float*)d_out);
}

// Round 18
// 110.259 us; speedup vs baseline: 1.0349x; 1.0349x over previous
//
#include <hip/hip_runtime.h>
#include <hip/hip_bf16.h>
#include <stdint.h>

#define NB 2
#define NS 2048
#define NDM 1024
#define NH 16
#define NHD 64
#define NTOK (NB * NS)  // 4096

typedef __bf16 bf16x8 __attribute__((ext_vector_type(8)));
typedef float f32x4 __attribute__((ext_vector_type(4)));
typedef uint16_t u16x8 __attribute__((ext_vector_type(8)));

static __device__ __forceinline__ uint16_t f2bf(float f) {
  __bf16 b = (__bf16)f;
  union { __bf16 b; uint16_t u; } x; x.b = b;
  return x.u;
}

static __device__ __forceinline__ u16x8 cvt8(float4 a, float4 b) {
  u16x8 v;
  v[0] = f2bf(a.x); v[1] = f2bf(a.y); v[2] = f2bf(a.z); v[3] = f2bf(a.w);
  v[4] = f2bf(b.x); v[5] = f2bf(b.y); v[6] = f2bf(b.z); v[7] = f2bf(b.w);
  return v;
}

static __device__ __forceinline__ void gload_lds16(const void* g, void* l) {
  __builtin_amdgcn_global_load_lds(
      (const __attribute__((address_space(1))) void*)g,
      (__attribute__((address_space(3))) void*)l, 16, 0, 0);
}

// ---------------------------------------------------------------------------
// Single fp32->bf16 convert pass over the 16M-element concat.
// ---------------------------------------------------------------------------
__global__ __launch_bounds__(256) void cvt_all(
    const float* __restrict__ wq, const float* __restrict__ wk,
    const float* __restrict__ wv, const float* __restrict__ wo,
    const float* __restrict__ q, const float* __restrict__ k,
    const float* __restrict__ v, uint16_t* __restrict__ WQB,
    uint16_t* __restrict__ WKB, uint16_t* __restrict__ WVB,
    uint16_t* __restrict__ WOB, uint16_t* __restrict__ XBQ,
    uint16_t* __restrict__ XBK, uint16_t* __restrict__ XBV) {
  size_t E = ((size_t)blockIdx.x * 256 + threadIdx.x) * 8;
  const float* src;
  uint16_t* dst;
  size_t off;
  if (E < (size_t)(4u << 20)) {
    int s = (int)(E >> 20);
    off = E & ((1u << 20) - 1);
    src = (s == 0) ? wq : (s == 1) ? wk : (s == 2) ? wv : wo;
    dst = (s == 0) ? WQB : (s == 1) ? WKB : (s == 2) ? WVB : WOB;
  } else {
    size_t E2 = E - ((size_t)4u << 20);
    int s = (int)(E2 >> 22);
    off = E2 & ((1u << 22) - 1);
    src = (s == 0) ? q : (s == 1) ? k : v;
    dst = (s == 0) ? XBQ : (s == 1) ? XBK : XBV;
  }
  float4 a = *(const float4*)(src + off);
  float4 b = *(const float4*)(src + off + 4);
  *(u16x8*)&dst[off] = cvt8(a, b);
}

// ---------------------------------------------------------------------------
// Projections: all-bf16, gload_lds both operands (both-sides XOR granule
// swizzle), dbuf LDS, 1 barrier/K-step, 2D grid (R16 config).
// z=0: XQ*0.125*log2e ; z=1: XK ; z=2: XVT (LDS-transposed, coalesced).
// ---------------------------------------------------------------------------
__global__ __launch_bounds__(256) void proj_gemm(
    const uint16_t* __restrict__ xbq, const uint16_t* __restrict__ xbk,
    const uint16_t* __restrict__ xbv, const uint16_t* __restrict__ wqb,
    const uint16_t* __restrict__ wkb, const uint16_t* __restrict__ wvb,
    uint16_t* __restrict__ XQ, uint16_t* __restrict__ XK,
    uint16_t* __restrict__ XVT) {
  __shared__ uint16_t SM[2][2][128][64];
  int z = blockIdx.z;
  const uint16_t* A = (z == 0) ? xbq : (z == 1) ? xbk : xbv;
  const uint16_t* W = (z == 0) ? wqb : (z == 1) ? wkb : wvb;
  int m0 = blockIdx.x * 128, n0 = blockIdx.y * 128;
  int tid = threadIdx.x;
  int lane = tid & 63, w = tid >> 6;
  int g = lane >> 4, r16 = lane & 15;
  int wm = w >> 1, wn = w & 1;
  int bce = ((lane & 7) ^ ((lane >> 3) & 7)) * 8;
  int brlane = lane >> 3;

  f32x4 acc[4][4] = {};

  #pragma unroll
  for (int i = 0; i < 4; ++i) {
    int row = w * 32 + i * 8;
    gload_lds16(A + (size_t)(m0 + row + brlane) * NDM + bce, &SM[0][0][row][0]);
    gload_lds16(W + (size_t)(n0 + row + brlane) * NDM + bce, &SM[0][1][row][0]);
  }
  __syncthreads();

  for (int t = 0; t < 16; ++t) {
    int cur = t & 1, nxt = cur ^ 1;
    if (t < 15) {
      int k1 = (t + 1) * 64;
      #pragma unroll
      for (int i = 0; i < 4; ++i) {
        int row = w * 32 + i * 8;
        gload_lds16(A + (size_t)(m0 + row + brlane) * NDM + k1 + bce,
                    &SM[nxt][0][row][0]);
        gload_lds16(W + (size_t)(n0 + row + brlane) * NDM + k1 + bce,
                    &SM[nxt][1][row][0]);
      }
    }

    #pragma unroll
    for (int kc = 0; kc < 2; ++kc) {
      bf16x8 af[4], bf[4];
      #pragma unroll
      for (int i = 0; i < 4; ++i) {
        int gran = (kc * 4 + g) ^ (r16 & 7);
        af[i] = *(const bf16x8*)&SM[cur][0][wm * 64 + i * 16 + r16][gran * 8];
        bf[i] = *(const bf16x8*)&SM[cur][1][wn * 64 + i * 16 + r16][gran * 8];
      }
      #pragma unroll
      for (int mi = 0; mi < 4; ++mi)
        #pragma unroll
        for (int ni = 0; ni < 4; ++ni)
          acc[mi][ni] = __builtin_amdgcn_mfma_f32_16x16x32_bf16(
              af[mi], bf[ni], acc[mi][ni], 0, 0, 0);
    }
    __syncthreads();
  }

  if (z == 2) {
    uint16_t* T = &SM[0][0][0][0];
    #pragma unroll
    for (int mi = 0; mi < 4; ++mi) {
      #pragma unroll
      for (int ni = 0; ni < 4; ++ni) {
        int tr = wn * 64 + ni * 16 + r16;
        int tc = wm * 64 + mi * 16 + g * 4;
        int gran = tc >> 3, sub = g & 1;
        f32x4 a = acc[mi][ni];
        ushort4 pk;
        pk.x = f2bf(a[0]); pk.y = f2bf(a[1]);
        pk.z = f2bf(a[2]); pk.w = f2bf(a[3]);
        *(ushort4*)(T + tr * 128 + ((gran ^ (tr & 7)) << 3) + (sub << 2)) = pk;
      }
    }
    __syncthreads();
    #pragma unroll
    for (int it = 0; it < 8; ++it) {
      int row = it * 16 + (tid >> 4);
      int grn = tid & 15;
      u16x8 vv = *(const u16x8*)(T + row * 128 + ((grn ^ (row & 7)) << 3));
      *(u16x8*)&XVT[(size_t)(n0 + row) * NTOK + m0 + grn * 8] = vv;
    }
  } else {
    float scale = (z == 0) ? 0.125f * 1.44269504088896340736f : 1.0f;
    uint16_t* Y = (z == 0) ? XQ : XK;
    #pragma unroll
    for (int mi = 0; mi < 4; ++mi) {
      #pragma unroll
      for (int ni = 0; ni < 4; ++ni) {
        int m = m0 + wm * 64 + mi * 16 + g * 4;
        int n = n0 + wn * 64 + ni * 16 + r16;
        f32x4 a = acc[mi][ni];
        #pragma unroll
        for (int j = 0; j < 4; ++j)
          Y[(size_t)(m + j) * NDM + n] = f2bf(a[j] * scale);
      }
    }
  }
}

// ---------------------------------------------------------------------------
// Causal flash attention v11 (R16, best measured 47.5 us): 4 waves x 16 q
// rows, heavy-first 1024 blocks, K/V staged via global_load_lds (waves 0-1
// K, 2-3 V; pre-swizzled source granule, linear dest, read-side XOR), dbuf
// + single barrier per tile, swapped QK^T lane-local softmax, T13, setprio.
// ---------------------------------------------------------------------------
__global__ __launch_bounds__(256) void attn_kernel(
    const uint16_t* __restrict__ XQ, const uint16_t* __restrict__ XK,
    const uint16_t* __restrict__ XVT, uint16_t* __restrict__ AO) {
  __shared__ uint16_t Klds[2][64][64];   // [buf][kv][d] linear (gload dest)
  __shared__ uint16_t Vlds[2][64][64];   // [buf][d][kv]
  __shared__ uint16_t Plds[4][16][72];

  int tid = threadIdx.x;
  int lane = tid & 63;
  int w = tid >> 6;
  int g = lane >> 4, r16 = lane & 15;
  int swz = r16 & 7;

  int item = (int)blockIdx.x;
  int qc = 31 - (item >> 5);    // heavy chunks dispatch first
  int bh = item & 31;
  int b = bh >> 4, h = bh & 15;
  int q0 = qc * 64;
  int q0w = q0 + w * 16;
  int T = qc + 1;               // kv tiles of 64

  const uint16_t* qb =
      XQ + (size_t)(b * NS + q0w + r16) * NDM + h * NHD + g * 8;
  bf16x8 qf0 = *(const bf16x8*)qb;
  bf16x8 qf1 = *(const bf16x8*)(qb + 32);

  f32x4 oacc[4] = {};               // O[q=g*4+j][d=dt*16+r16]
  float mrow = -1e30f, lsum = 0.f;  // per-lane: q = r16

  int srl = lane >> 3;
  int bce = ((lane & 7) ^ srl) * 8;
  const uint16_t* kstg = XK + (size_t)(b * NS + srl) * NDM + h * NHD + bce;
  const uint16_t* vstg = XVT + (size_t)(h * NHD + srl) * NTOK + b * NS + bce;
  int stgrow = (w & 1) * 32;

  // prologue: stage tile 0 into buf 0 (waves 0-1: K, waves 2-3: V)
  if (w < 2) {
    #pragma unroll
    for (int i = 0; i < 4; ++i)
      gload_lds16(kstg + (size_t)(stgrow + i * 8) * NDM,
                  &Klds[0][stgrow + i * 8][0]);
  } else {
    #pragma unroll
    for (int i = 0; i < 4; ++i)
      gload_lds16(vstg + (size_t)(stgrow + i * 8) * NTOK,
                  &Vlds[0][stgrow + i * 8][0]);
  }

  for (int t = 0; t < T; ++t) {
    int kv0 = t * 64;
    int cur = t & 1;
    __syncthreads();  // drains stage gloads for tile t; prev-buf reads done
    if (t + 1 < T) {  // stage tile t+1 into the other buffer
      int kv1 = kv0 + 64;
      if (w < 2) {
        #pragma unroll
        for (int i = 0; i < 4; ++i)
          gload_lds16(kstg + (size_t)(kv1 + stgrow + i * 8) * NDM,
                      &Klds[cur ^ 1][stgrow + i * 8][0]);
      } else {
        #pragma unroll
        for (int i = 0; i < 4; ++i)
          gload_lds16(vstg + kv1 + (size_t)(stgrow + i * 8) * NTOK,
                      &Vlds[cur ^ 1][stgrow + i * 8][0]);
      }
    }

    // ---- QK^T swapped: col=r16=q, row=g*4+j=kv_local ----
    f32x4 sc[4];
    __builtin_amdgcn_s_setprio(1);
    #pragma unroll
    for (int t4 = 0; t4 < 4; ++t4) {
      bf16x8 kf0 = *(const bf16x8*)&Klds[cur][t4 * 16 + r16][(g ^ swz) * 8];
      bf16x8 kf1 = *(const bf16x8*)&Klds[cur][t4 * 16 + r16][((4 + g) ^ swz) * 8];
      f32x4 x = __builtin_amdgcn_mfma_f32_16x16x32_bf16(
          kf0, qf0, (f32x4){0.f, 0.f, 0.f, 0.f}, 0, 0, 0);
      x = __builtin_amdgcn_mfma_f32_16x16x32_bf16(kf1, qf1, x, 0, 0, 0);
      sc[t4] = x;
    }
    __builtin_amdgcn_s_setprio(0);

    // ---- causal mask (diag subtiles only; kv = kv0+t4*16+g*4+j, q = r16) ----
    #pragma unroll
    for (int t4 = 0; t4 < 4; ++t4) {
      if (kv0 + t4 * 16 + 15 > q0w) {  // wave-uniform guard
        #pragma unroll
        for (int j = 0; j < 4; ++j)
          if (kv0 + t4 * 16 + g * 4 + j > q0w + r16) sc[t4][j] = -1e30f;
      }
    }

    // ---- lane-local row max + cross-group combine ----
    float m16 = fmaxf(
        fmaxf(fmaxf(fmaxf(sc[0][0], sc[0][1]), fmaxf(sc[0][2], sc[0][3])),
              fmaxf(fmaxf(sc[1][0], sc[1][1]), fmaxf(sc[1][2], sc[1][3]))),
        fmaxf(fmaxf(fmaxf(sc[2][0], sc[2][1]), fmaxf(sc[2][2], sc[2][3])),
              fmaxf(fmaxf(sc[3][0], sc[3][1]), fmaxf(sc[3][2], sc[3][3]))));
    m16 = fmaxf(m16, __shfl_xor(m16, 16));
    m16 = fmaxf(m16, __shfl_xor(m16, 32));

    // ---- T13 defer-rescale (THR=8 in exp2 domain) ----
    if (!__all(m16 <= mrow + 8.0f)) {
      float mnew = fmaxf(mrow, m16);
      float sf = __builtin_amdgcn_exp2f(mrow - mnew);
      mrow = mnew;
      lsum *= sf;
      #pragma unroll
      for (int j = 0; j < 4; ++j) {
        float sfj = __shfl(sf, g * 4 + j);
        #pragma unroll
        for (int dt = 0; dt < 4; ++dt) oacc[dt][j] *= sfj;
      }
    }

    // ---- P = exp2(S - m), per-lane partial sum, pack to LDS ----
    #pragma unroll
    for (int t4 = 0; t4 < 4; ++t4) {
      float p0 = __builtin_amdgcn_exp2f(sc[t4][0] - mrow);
      float p1 = __builtin_amdgcn_exp2f(sc[t4][1] - mrow);
      float p2 = __builtin_amdgcn_exp2f(sc[t4][2] - mrow);
      float p3 = __builtin_amdgcn_exp2f(sc[t4][3] - mrow);
      lsum += (p0 + p1) + (p2 + p3);
      ushort4 pk;
      pk.x = f2bf(p0); pk.y = f2bf(p1); pk.z = f2bf(p2); pk.w = f2bf(p3);
      *(ushort4*)&Plds[w][r16][t4 * 16 + g * 4] = pk;
    }

    // ---- PV ----
    bf16x8 pa0 = *(const bf16x8*)&Plds[w][r16][g * 8];
    bf16x8 pa1 = *(const bf16x8*)&Plds[w][r16][32 + g * 8];
    __builtin_amdgcn_s_setprio(1);
    #pragma unroll
    for (int dt = 0; dt < 4; ++dt) {
      bf16x8 vf0 = *(const bf16x8*)&Vlds[cur][dt * 16 + r16][(g ^ swz) * 8];
      bf16x8 vf1 = *(const bf16x8*)&Vlds[cur][dt * 16 + r16][((4 + g) ^ swz) * 8];
      oacc[dt] = __builtin_amdgcn_mfma_f32_16x16x32_bf16(pa0, vf0, oacc[dt], 0, 0, 0);
      oacc[dt] = __builtin_amdgcn_mfma_f32_16x16x32_bf16(pa1, vf1, oacc[dt], 0, 0, 0);
    }
    __builtin_amdgcn_s_setprio(0);
  }

  // ---- epilogue: cross-group l reduce, redistribute, normalize, store ----
  float l2 = lsum + __shfl_xor(lsum, 16);
  float ltot = l2 + __shfl_xor(l2, 32);
  #pragma unroll
  for (int j = 0; j < 4; ++j) {
    float lt = __shfl(ltot, g * 4 + j);
    float inv = 1.0f / lt;
    size_t ro = (size_t)(b * NS + q0 + w * 16 + g * 4 + j) * NDM + h * NHD;
    #pragma unroll
    for (int dt = 0; dt < 4; ++dt)
      AO[ro + dt * 16 + r16] = f2bf(oacc[dt][j] * inv);
  }
}

// ---------------------------------------------------------------------------
// Output projection (R16 config, 2D grid).
// ---------------------------------------------------------------------------
__global__ __launch_bounds__(256) void out_gemm(
    const uint16_t* __restrict__ AO, const uint16_t* __restrict__ wob,
    float* __restrict__ out) {
  __shared__ uint16_t As[2][128][64];
  __shared__ uint16_t Bs[2][128][64];
  int m0 = blockIdx.x * 128, n0 = blockIdx.y * 128;
  int tid = threadIdx.x;
  int lane = tid & 63, w = tid >> 6;
  int g = lane >> 4, r16 = lane & 15;
  int wm = w >> 1, wn = w & 1;
  int bce = ((lane & 7) ^ ((lane >> 3) & 7)) * 8;
  int brlane = lane >> 3;

  f32x4 acc[4][4] = {};

  #pragma unroll
  for (int i = 0; i < 4; ++i) {
    int row = w * 32 + i * 8;
    gload_lds16(AO + (size_t)(m0 + row + brlane) * NDM + bce, &As[0][row][0]);
    gload_lds16(wob + (size_t)(n0 + row + brlane) * NDM + bce, &Bs[0][row][0]);
  }
  __syncthreads();

  for (int t = 0; t < 16; ++t) {
    int cur = t & 1, nxt = cur ^ 1;
    if (t < 15) {
      int k1 = (t + 1) * 64;
      #pragma unroll
      for (int i = 0; i < 4; ++i) {
        int row = w * 32 + i * 8;
        gload_lds16(AO + (size_t)(m0 + row + brlane) * NDM + k1 + bce,
                    &As[nxt][row][0]);
        gload_lds16(wob + (size_t)(n0 + row + brlane) * NDM + k1 + bce,
                    &Bs[nxt][row][0]);
      }
    }

    #pragma unroll
    for (int kc = 0; kc < 2; ++kc) {
      bf16x8 af[4], bf[4];
      #pragma unroll
      for (int i = 0; i < 4; ++i) {
        int gran = (kc * 4 + g) ^ (r16 & 7);
        af[i] = *(const bf16x8*)&As[cur][wm * 64 + i * 16 + r16][gran * 8];
        bf[i] = *(const bf16x8*)&Bs[cur][wn * 64 + i * 16 + r16][gran * 8];
      }
      #pragma unroll
      for (int mi = 0; mi < 4; ++mi)
        #pragma unroll
        for (int ni = 0; ni < 4; ++ni)
          acc[mi][ni] = __builtin_amdgcn_mfma_f32_16x16x32_bf16(
              af[mi], bf[ni], acc[mi][ni], 0, 0, 0);
    }
    __syncthreads();
  }

  #pragma unroll
  for (int mi = 0; mi < 4; ++mi) {
    #pragma unroll
    for (int ni = 0; ni < 4; ++ni) {
      int m = m0 + wm * 64 + mi * 16 + g * 4;
      int n = n0 + wn * 64 + ni * 16 + r16;
      #pragma unroll
      for (int j = 0; j < 4; ++j)
        out[(size_t)(m + j) * NDM + n] = acc[mi][ni][j];
    }
  }
}

extern "C" void kernel_launch(void* const* d_in, const int* in_sizes, int n_in,
                              void* d_out, int out_size, void* d_ws,
                              size_t ws_size, hipStream_t stream) {
  const float* q  = (const float*)d_in[0];
  const float* k  = (const float*)d_in[1];
  const float* v  = (const float*)d_in[2];
  const float* wq = (const float*)d_in[3];
  const float* wk = (const float*)d_in[4];
  const float* wv = (const float*)d_in[5];
  const float* wo = (const float*)d_in[6];

  const size_t XN = (size_t)NTOK * NDM;  // 4M elems
  const size_t WN = (size_t)NDM * NDM;   // 1M elems
  uint16_t* XQ  = (uint16_t*)d_ws;       // [NTOK][NDM] bf16 (pre-scaled)
  uint16_t* XK  = XQ + XN;               // [NTOK][NDM]
  uint16_t* XVT = XK + XN;               // [NDM][NTOK]
  uint16_t* WQB = XVT + XN;              // bf16 weights, 4 x [NDM][NDM]
  uint16_t* WKB = WQB + WN;
  uint16_t* WVB = WKB + WN;
  uint16_t* WOB = WVB + WN;
  uint16_t* XBQ = WOB + WN;              // bf16 activations, 3 x [NTOK][NDM]
  uint16_t* XBK = XBQ + XN;
  uint16_t* XBV = XBK + XN;
  uint16_t* AO  = XBQ;  // alias: XBQ dead after proj_gemm

  cvt_all<<<dim3(8192), 256, 0, stream>>>(
      wq, wk, wv, wo, q, k, v, WQB, WKB, WVB, WOB, XBQ, XBK, XBV);
  proj_gemm<<<dim3(NTOK / 128, NDM / 128, 3), 256, 0, stream>>>(
      XBQ, XBK, XBV, WQB, WKB, WVB, XQ, XK, XVT);
  attn_kernel<<<dim3(1024), 256, 0, stream>>>(XQ, XK, XVT, AO);
  out_gemm<<<dim3(NTOK / 128, NDM / 128), 256, 0, stream>>>(
      AO, WOB, (float*)d_out);
}